// Round 1
// baseline (991.390 us; speedup 1.0000x reference)
//
#include <hip/hip_runtime.h>

#define NB   256
#define NT   512
#define DHX  100   // DX
#define DHZ  100   // DZ
#define NH1  10
#define NH2  10
#define NDZ  20
#define NDX  20
#define DOUT 500

__device__ __forceinline__ float sgm(float v) { return 1.f / (1.f + __expf(-v)); }
__device__ __forceinline__ float tnh(float v) {
    v = fminf(fmaxf(v, -15.f), 15.f);
    float e = __expf(2.f * v);
    return (e - 1.f) / (e + 1.f);
}
__device__ __forceinline__ float sftp(float v) {
    // softplus(v) = max(v,0) + log1p(exp(-|v|))  (abs err < 1e-7 with __logf)
    return fmaxf(v, 0.f) + __logf(1.f + __expf(-fabsf(v)));
}

// One block (128 threads = 2 waves) per batch element.
// wave0: h1 recurrence (dz MLP -> z reparam -> GRU1) + z_loc/z_scale/z_t outputs
// wave1: h2 recurrence (GRU2 over x) + dx MLP (one step behind) + x_loc/x_scale outputs
__global__ __launch_bounds__(128, 1) void arfssm(
    const float* __restrict__ x, const float* __restrict__ eps,
    const float* __restrict__ W_ih1, const float* __restrict__ W_hh1,
    const float* __restrict__ b_ih1, const float* __restrict__ b_hh1,
    const float* __restrict__ W_ih2, const float* __restrict__ W_hh2,
    const float* __restrict__ b_ih2, const float* __restrict__ b_hh2,
    const float* __restrict__ dz_W1, const float* __restrict__ dz_b1,
    const float* __restrict__ dz_Wloc, const float* __restrict__ dz_bloc,
    const float* __restrict__ dz_Wscale, const float* __restrict__ dz_bscale,
    const float* __restrict__ dx_W1, const float* __restrict__ dx_b1,
    const float* __restrict__ dx_Wloc, const float* __restrict__ dx_bloc,
    const float* __restrict__ dx_Wscale, const float* __restrict__ dx_bscale,
    const float* __restrict__ h1_0, const float* __restrict__ h2_0,
    float* __restrict__ out)
{
    __shared__ __align__(16) float xbuf[2][104];  // x row double buffer (pad->0)
    __shared__ __align__(16) float zbuf[104];     // z_t (pad->0)
    __shared__ __align__(16) float hdzs[20];
    __shared__ __align__(16) float hdxs[20];
    __shared__ __align__(16) float h1d[2][12];    // h1n double buffer
    __shared__ __align__(16) float h2new[12];
    __shared__ __align__(16) float gA[32];        // gi1 (incl b_ih1)
    __shared__ __align__(16) float gB[32];        // gh1 (incl b_hh1)
    __shared__ __align__(16) float gA2[32];
    __shared__ __align__(16) float gB2[32];

    const int tid = threadIdx.x;
    const int b   = blockIdx.x;

    if (tid < 64) {
        // ============================ WAVE 0 ============================
        const int l = tid;

        // ---- per-lane weight preload (loop-invariant) ----
        float wdz1[10]; float bdz1 = 0.f;
        #pragma unroll
        for (int k = 0; k < 10; ++k) wdz1[k] = 0.f;
        if (l < 20) {
            #pragma unroll
            for (int k = 0; k < 10; ++k) wdz1[k] = dz_W1[l * 10 + k];
            bdz1 = dz_b1[l];
        }
        float wzl1[20], wzs1[20];
        #pragma unroll
        for (int k = 0; k < 20; ++k) { wzl1[k] = dz_Wloc[l * 20 + k]; wzs1[k] = dz_Wscale[l * 20 + k]; }
        const float bzl1 = dz_bloc[l], bzs1 = dz_bscale[l];
        float wzl2[20], wzs2[20]; float bzl2 = 0.f, bzs2 = 0.f;
        #pragma unroll
        for (int k = 0; k < 20; ++k) { wzl2[k] = 0.f; wzs2[k] = 0.f; }
        if (l < 36) {
            const int j2 = l + 64;
            #pragma unroll
            for (int k = 0; k < 20; ++k) { wzl2[k] = dz_Wloc[j2 * 20 + k]; wzs2[k] = dz_Wscale[j2 * 20 + k]; }
            bzl2 = dz_bloc[j2]; bzs2 = dz_bscale[j2];
        }
        const int gi_i = l >> 1, gi_h = l & 1;
        float wA[52]; float bihA = 0.f, bhh1r = 0.f; float whh1r[10];
        #pragma unroll
        for (int k = 0; k < 52; ++k) wA[k] = 0.f;
        #pragma unroll
        for (int k = 0; k < 10; ++k) whh1r[k] = 0.f;
        if (l < 60) {
            const int k0 = gi_h ? 52 : 0;
            const int kn = gi_h ? 48 : 52;
            #pragma unroll
            for (int k = 0; k < 52; ++k) if (k < kn) wA[k] = W_ih1[gi_i * 100 + k0 + k];
            bihA = b_ih1[gi_i];
            if (gi_h == 0) {
                #pragma unroll
                for (int k = 0; k < 10; ++k) whh1r[k] = W_hh1[gi_i * 10 + k];
                bhh1r = b_hh1[gi_i];
            }
        }

        // ---- prologue ----
        if (l < 10) { h1d[1][l] = h1_0[l]; h1d[0][l] = 0.f; }
        if (l < 4)  zbuf[100 + l] = 0.f;
        float e1c = eps[(size_t)b * NT * DHZ + l];
        float e2c = 0.f;
        if (l < 36) e2c = eps[(size_t)b * NT * DHZ + 64 + l];
        __syncthreads();

        for (int t = 0; t < NT; ++t) {
            // refresh replicated h1 (= h1n(t-1))
            const int pr = (t & 1) ^ 1;
            float h1r[10];
            {
                float4 a = *(const float4*)&h1d[pr][0];
                float4 c = *(const float4*)&h1d[pr][4];
                h1r[0]=a.x; h1r[1]=a.y; h1r[2]=a.z; h1r[3]=a.w;
                h1r[4]=c.x; h1r[5]=c.y; h1r[6]=c.z; h1r[7]=c.w;
                h1r[8]=h1d[pr][8]; h1r[9]=h1d[pr][9];
            }
            // prefetch eps(t+1)
            const int tn = (t + 1 < NT) ? (t + 1) : t;
            const float* ern = eps + ((size_t)b * NT + tn) * DHZ;
            float e1n = ern[l];
            float e2n = 0.f;
            if (l < 36) e2n = ern[64 + l];

            // hdz = relu(dz_W1 @ h1 + b)
            if (l < 20) {
                float v = bdz1;
                #pragma unroll
                for (int k = 0; k < 10; ++k) v = fmaf(wdz1[k], h1r[k], v);
                hdzs[l] = fmaxf(v, 0.f);
            }
            __builtin_amdgcn_wave_barrier();
            float hdzr[20];
            #pragma unroll
            for (int q = 0; q < 5; ++q) {
                float4 h4 = *(const float4*)&hdzs[4 * q];
                hdzr[4*q]=h4.x; hdzr[4*q+1]=h4.y; hdzr[4*q+2]=h4.z; hdzr[4*q+3]=h4.w;
            }

            const size_t ob = ((size_t)b * NT + t) * DOUT;
            // z_loc/z_scale/z_t : unit1 (j = l)
            {
                float vl = bzl1, vs = bzs1;
                #pragma unroll
                for (int k = 0; k < 20; ++k) { vl = fmaf(wzl1[k], hdzr[k], vl); vs = fmaf(wzs1[k], hdzr[k], vs); }
                float sp = sftp(vs);
                float zt = fmaf(sp, e1c, vl);
                zbuf[l] = zt;
                out[ob + 200 + l] = vl;
                out[ob + 300 + l] = sp;
                out[ob + 400 + l] = zt;
            }
            // unit2 (j = l + 64)
            if (l < 36) {
                float vl = bzl2, vs = bzs2;
                #pragma unroll
                for (int k = 0; k < 20; ++k) { vl = fmaf(wzl2[k], hdzr[k], vl); vs = fmaf(wzs2[k], hdzr[k], vs); }
                float sp = sftp(vs);
                float zt = fmaf(sp, e2c, vl);
                zbuf[64 + l] = zt;
                out[ob + 264 + l] = vl;
                out[ob + 364 + l] = sp;
                out[ob + 464 + l] = zt;
            }
            e1c = e1n; e2c = e2n;
            __builtin_amdgcn_wave_barrier();

            // gi1 = W_ih1 @ z_t (split-K over lane pairs), gh1 = W_hh1 @ h1
            if (l < 60) {
                const float4* z4 = (const float4*)zbuf;
                const int b4 = gi_h ? 13 : 0;
                float a0=0.f, a1=0.f, a2=0.f, a3=0.f;
                #pragma unroll
                for (int q = 0; q < 13; ++q) {
                    float4 zz = z4[b4 + q];
                    a0 = fmaf(wA[4*q+0], zz.x, a0);
                    a1 = fmaf(wA[4*q+1], zz.y, a1);
                    a2 = fmaf(wA[4*q+2], zz.z, a2);
                    a3 = fmaf(wA[4*q+3], zz.w, a3);
                }
                float acc = (a0 + a1) + (a2 + a3);
                acc += __shfl_xor(acc, 1, 64);
                if (gi_h == 0) {
                    float gh = bhh1r;
                    #pragma unroll
                    for (int k = 0; k < 10; ++k) gh = fmaf(whh1r[k], h1r[k], gh);
                    gA[gi_i] = acc + bihA;
                    gB[gi_i] = gh;
                }
            }
            __builtin_amdgcn_wave_barrier();

            // GRU1 gates (PyTorch order r,z,n) -> h1n
            if (l < 10) {
                float r = sgm(gA[l] + gB[l]);
                float u = sgm(gA[l + 10] + gB[l + 10]);
                float n = tnh(fmaf(r, gB[l + 20], gA[l + 20]));
                h1d[t & 1][l] = (1.f - u) * n + u * h1r[l];
            }
            __syncthreads();
        }
    } else {
        // ============================ WAVE 1 ============================
        const int l = tid - 64;

        // ---- per-lane weight preload ----
        float wdx1[20]; float bdx1 = 0.f;
        #pragma unroll
        for (int k = 0; k < 20; ++k) wdx1[k] = 0.f;
        if (l < 20) {
            #pragma unroll
            for (int k = 0; k < 20; ++k) wdx1[k] = dx_W1[l * 20 + k];
            bdx1 = dx_b1[l];
        }
        float wxl1[20], wxs1[20];
        #pragma unroll
        for (int k = 0; k < 20; ++k) { wxl1[k] = dx_Wloc[l * 20 + k]; wxs1[k] = dx_Wscale[l * 20 + k]; }
        const float bxl1 = dx_bloc[l], bxs1 = dx_bscale[l];
        float wxl2[20], wxs2[20]; float bxl2 = 0.f, bxs2 = 0.f;
        #pragma unroll
        for (int k = 0; k < 20; ++k) { wxl2[k] = 0.f; wxs2[k] = 0.f; }
        if (l < 36) {
            const int j2 = l + 64;
            #pragma unroll
            for (int k = 0; k < 20; ++k) { wxl2[k] = dx_Wloc[j2 * 20 + k]; wxs2[k] = dx_Wscale[j2 * 20 + k]; }
            bxl2 = dx_bloc[j2]; bxs2 = dx_bscale[j2];
        }
        const int gi_i = l >> 1, gi_h = l & 1;
        float wB[52]; float bihB = 0.f, bhh2r = 0.f; float whh2r[10];
        #pragma unroll
        for (int k = 0; k < 52; ++k) wB[k] = 0.f;
        #pragma unroll
        for (int k = 0; k < 10; ++k) whh2r[k] = 0.f;
        if (l < 60) {
            const int k0 = gi_h ? 52 : 0;
            const int kn = gi_h ? 48 : 52;
            #pragma unroll
            for (int k = 0; k < 52; ++k) if (k < kn) wB[k] = W_ih2[gi_i * 100 + k0 + k];
            bihB = b_ih2[gi_i];
            if (gi_h == 0) {
                #pragma unroll
                for (int k = 0; k < 10; ++k) whh2r[k] = W_hh2[gi_i * 10 + k];
                bhh2r = b_hh2[gi_i];
            }
        }
        float h2r[10], h2pr[10];
        #pragma unroll
        for (int k = 0; k < 10; ++k) { h2r[k] = h2_0[k]; h2pr[k] = h2_0[k]; }

        // ---- prologue: x row 0 into xbuf[0], row 1 into vh ----
        if (l < 4) { xbuf[0][100 + l] = 0.f; xbuf[1][100 + l] = 0.f; }
        float4 vh = make_float4(0.f, 0.f, 0.f, 0.f);
        {
            const float4* xr0 = (const float4*)(x + (size_t)b * NT * DHX);
            const float4* xr1 = (const float4*)(x + ((size_t)b * NT + 1) * DHX);
            if (l < 25) {
                float4 v0 = xr0[l];
                vh = xr1[l];
                *((float4*)&xbuf[0][0] + l) = v0;
            }
        }
        __syncthreads();

        for (int t = 0; t < NT; ++t) {
            // publish x(t+1) into the other slot; prefetch x(t+2)
            if (l < 25) *((float4*)&xbuf[(t + 1) & 1][0] + l) = vh;
            {
                const int tn = (t + 2 < NT) ? (t + 2) : (NT - 1);
                const float4* xr = (const float4*)(x + ((size_t)b * NT + tn) * DHX);
                if (l < 25) vh = xr[l];
            }

            // dx MLP for step t-1 (uses h1n(t-1) from LDS, h2_shift(t-1) = h2pr)
            if (t > 0) {
                const int pr = (t & 1) ^ 1;
                if (l < 20) {
                    float4 a = *(const float4*)&h1d[pr][0];
                    float4 c = *(const float4*)&h1d[pr][4];
                    float v = bdx1;
                    v = fmaf(wdx1[0], a.x, v); v = fmaf(wdx1[1], a.y, v);
                    v = fmaf(wdx1[2], a.z, v); v = fmaf(wdx1[3], a.w, v);
                    v = fmaf(wdx1[4], c.x, v); v = fmaf(wdx1[5], c.y, v);
                    v = fmaf(wdx1[6], c.z, v); v = fmaf(wdx1[7], c.w, v);
                    v = fmaf(wdx1[8], h1d[pr][8], v); v = fmaf(wdx1[9], h1d[pr][9], v);
                    #pragma unroll
                    for (int k = 0; k < 10; ++k) v = fmaf(wdx1[10 + k], h2pr[k], v);
                    hdxs[l] = fmaxf(v, 0.f);
                }
                __builtin_amdgcn_wave_barrier();
                float hdxr[20];
                #pragma unroll
                for (int q = 0; q < 5; ++q) {
                    float4 h4 = *(const float4*)&hdxs[4 * q];
                    hdxr[4*q]=h4.x; hdxr[4*q+1]=h4.y; hdxr[4*q+2]=h4.z; hdxr[4*q+3]=h4.w;
                }
                const size_t ob = ((size_t)b * NT + (t - 1)) * DOUT;
                {
                    float vl = bxl1, vs = bxs1;
                    #pragma unroll
                    for (int k = 0; k < 20; ++k) { vl = fmaf(wxl1[k], hdxr[k], vl); vs = fmaf(wxs1[k], hdxr[k], vs); }
                    out[ob + l]       = vl;
                    out[ob + 100 + l] = sftp(vs);
                }
                if (l < 36) {
                    float vl = bxl2, vs = bxs2;
                    #pragma unroll
                    for (int k = 0; k < 20; ++k) { vl = fmaf(wxl2[k], hdxr[k], vl); vs = fmaf(wxs2[k], hdxr[k], vs); }
                    out[ob + 64 + l]  = vl;
                    out[ob + 164 + l] = sftp(vs);
                }
            }

            // save h2_shift(t) before updating
            #pragma unroll
            for (int k = 0; k < 10; ++k) h2pr[k] = h2r[k];

            // gi2 = W_ih2 @ x_t (split-K), gh2 = W_hh2 @ h2
            if (l < 60) {
                const float4* x4 = (const float4*)&xbuf[t & 1][0];
                const int b4 = gi_h ? 13 : 0;
                float a0=0.f, a1=0.f, a2=0.f, a3=0.f;
                #pragma unroll
                for (int q = 0; q < 13; ++q) {
                    float4 xx = x4[b4 + q];
                    a0 = fmaf(wB[4*q+0], xx.x, a0);
                    a1 = fmaf(wB[4*q+1], xx.y, a1);
                    a2 = fmaf(wB[4*q+2], xx.z, a2);
                    a3 = fmaf(wB[4*q+3], xx.w, a3);
                }
                float acc = (a0 + a1) + (a2 + a3);
                acc += __shfl_xor(acc, 1, 64);
                if (gi_h == 0) {
                    float gh = bhh2r;
                    #pragma unroll
                    for (int k = 0; k < 10; ++k) gh = fmaf(whh2r[k], h2r[k], gh);
                    gA2[gi_i] = acc + bihB;
                    gB2[gi_i] = gh;
                }
            }
            __builtin_amdgcn_wave_barrier();
            if (l < 10) {
                float r = sgm(gA2[l] + gB2[l]);
                float u = sgm(gA2[l + 10] + gB2[l + 10]);
                float n = tnh(fmaf(r, gB2[l + 20], gA2[l + 20]));
                h2new[l] = (1.f - u) * n + u * h2r[l];
            }
            __builtin_amdgcn_wave_barrier();
            {
                float4 a = *(const float4*)&h2new[0];
                float4 c = *(const float4*)&h2new[4];
                h2r[0]=a.x; h2r[1]=a.y; h2r[2]=a.z; h2r[3]=a.w;
                h2r[4]=c.x; h2r[5]=c.y; h2r[6]=c.z; h2r[7]=c.w;
                h2r[8]=h2new[8]; h2r[9]=h2new[9];
            }
            __syncthreads();
        }

        // ---- epilogue: dx for step T-1 ----
        {
            const int pr = (NT - 1) & 1;
            if (l < 20) {
                float4 a = *(const float4*)&h1d[pr][0];
                float4 c = *(const float4*)&h1d[pr][4];
                float v = bdx1;
                v = fmaf(wdx1[0], a.x, v); v = fmaf(wdx1[1], a.y, v);
                v = fmaf(wdx1[2], a.z, v); v = fmaf(wdx1[3], a.w, v);
                v = fmaf(wdx1[4], c.x, v); v = fmaf(wdx1[5], c.y, v);
                v = fmaf(wdx1[6], c.z, v); v = fmaf(wdx1[7], c.w, v);
                v = fmaf(wdx1[8], h1d[pr][8], v); v = fmaf(wdx1[9], h1d[pr][9], v);
                #pragma unroll
                for (int k = 0; k < 10; ++k) v = fmaf(wdx1[10 + k], h2pr[k], v);
                hdxs[l] = fmaxf(v, 0.f);
            }
            __builtin_amdgcn_wave_barrier();
            float hdxr[20];
            #pragma unroll
            for (int q = 0; q < 5; ++q) {
                float4 h4 = *(const float4*)&hdxs[4 * q];
                hdxr[4*q]=h4.x; hdxr[4*q+1]=h4.y; hdxr[4*q+2]=h4.z; hdxr[4*q+3]=h4.w;
            }
            const size_t ob = ((size_t)b * NT + (NT - 1)) * DOUT;
            {
                float vl = bxl1, vs = bxs1;
                #pragma unroll
                for (int k = 0; k < 20; ++k) { vl = fmaf(wxl1[k], hdxr[k], vl); vs = fmaf(wxs1[k], hdxr[k], vs); }
                out[ob + l]       = vl;
                out[ob + 100 + l] = sftp(vs);
            }
            if (l < 36) {
                float vl = bxl2, vs = bxs2;
                #pragma unroll
                for (int k = 0; k < 20; ++k) { vl = fmaf(wxl2[k], hdxr[k], vl); vs = fmaf(wxs2[k], hdxr[k], vs); }
                out[ob + 64 + l]  = vl;
                out[ob + 164 + l] = sftp(vs);
            }
        }
    }
}

extern "C" void kernel_launch(void* const* d_in, const int* in_sizes, int n_in,
                              void* d_out, int out_size, void* d_ws, size_t ws_size,
                              hipStream_t stream) {
    (void)in_sizes; (void)n_in; (void)out_size; (void)d_ws; (void)ws_size;
    const float* x         = (const float*)d_in[0];
    const float* eps       = (const float*)d_in[1];
    const float* W_ih1     = (const float*)d_in[2];
    const float* W_hh1     = (const float*)d_in[3];
    const float* b_ih1     = (const float*)d_in[4];
    const float* b_hh1     = (const float*)d_in[5];
    const float* W_ih2     = (const float*)d_in[6];
    const float* W_hh2     = (const float*)d_in[7];
    const float* b_ih2     = (const float*)d_in[8];
    const float* b_hh2     = (const float*)d_in[9];
    const float* dz_W1     = (const float*)d_in[10];
    const float* dz_b1     = (const float*)d_in[11];
    const float* dz_Wloc   = (const float*)d_in[12];
    const float* dz_bloc   = (const float*)d_in[13];
    const float* dz_Wscale = (const float*)d_in[14];
    const float* dz_bscale = (const float*)d_in[15];
    const float* dx_W1     = (const float*)d_in[16];
    const float* dx_b1     = (const float*)d_in[17];
    const float* dx_Wloc   = (const float*)d_in[18];
    const float* dx_bloc   = (const float*)d_in[19];
    const float* dx_Wscale = (const float*)d_in[20];
    const float* dx_bscale = (const float*)d_in[21];
    const float* h1_0      = (const float*)d_in[22];
    const float* h2_0      = (const float*)d_in[23];

    arfssm<<<NB, 128, 0, stream>>>(x, eps, W_ih1, W_hh1, b_ih1, b_hh1,
                                   W_ih2, W_hh2, b_ih2, b_hh2,
                                   dz_W1, dz_b1, dz_Wloc, dz_bloc, dz_Wscale, dz_bscale,
                                   dx_W1, dx_b1, dx_Wloc, dx_bloc, dx_Wscale, dx_bscale,
                                   h1_0, h2_0, (float*)d_out);
}

// Round 2
// 887.368 us; speedup vs baseline: 1.1172x; 1.1172x over previous
//
#include <hip/hip_runtime.h>

#define NB   256
#define NT   512
#define DHX  100   // DX
#define DHZ  100   // DZ
#define DOUT 500
#define WIN  8     // steps per sync window
#define RING 16    // h1 ring depth (2 windows)

__device__ __forceinline__ float sgm(float v) { return 1.f / (1.f + __expf(-v)); }
__device__ __forceinline__ float tnh(float v) {
    v = fminf(fmaxf(v, -15.f), 15.f);
    float e = __expf(2.f * v);
    return (e - 1.f) / (e + 1.f);
}
__device__ __forceinline__ float sftp(float v) {
    return fmaxf(v, 0.f) + __logf(1.f + __expf(-fabsf(v)));
}

// One block (128 threads = 2 waves) per batch element.
// wave0: h1 recurrence (dz MLP -> z reparam -> GRU1) + z outputs.
// wave1: h2 recurrence (GRU2 over x) + dx MLP + x outputs, one 8-step WINDOW
//        behind wave0 (reads h1 from a 16-deep LDS ring).
// __syncthreads only once per window -> vmcnt(0) drain amortized 8x.
__global__ __launch_bounds__(128, 1) void arfssm(
    const float* __restrict__ x, const float* __restrict__ eps,
    const float* __restrict__ W_ih1, const float* __restrict__ W_hh1,
    const float* __restrict__ b_ih1, const float* __restrict__ b_hh1,
    const float* __restrict__ W_ih2, const float* __restrict__ W_hh2,
    const float* __restrict__ b_ih2, const float* __restrict__ b_hh2,
    const float* __restrict__ dz_W1, const float* __restrict__ dz_b1,
    const float* __restrict__ dz_Wloc, const float* __restrict__ dz_bloc,
    const float* __restrict__ dz_Wscale, const float* __restrict__ dz_bscale,
    const float* __restrict__ dx_W1, const float* __restrict__ dx_b1,
    const float* __restrict__ dx_Wloc, const float* __restrict__ dx_bloc,
    const float* __restrict__ dx_Wscale, const float* __restrict__ dx_bscale,
    const float* __restrict__ h1_0, const float* __restrict__ h2_0,
    float* __restrict__ out)
{
    __shared__ __align__(16) float h1d[RING][12];  // h1 state ring: slot k = h1 after k steps (mod 16)
    __shared__ __align__(16) float xbuf[2][104];   // wave1-private x row double buffer
    __shared__ __align__(16) float zbuf[104];      // wave0-private z_t
    __shared__ __align__(16) float hdzs[20];       // wave0-private
    __shared__ __align__(16) float hdxs[20];       // wave1-private
    __shared__ __align__(16) float h2new[12];      // wave1-private
    __shared__ __align__(16) float gA[32];         // wave0-private gi1
    __shared__ __align__(16) float gB[32];         // wave0-private gh1
    __shared__ __align__(16) float gA2[32];        // wave1-private
    __shared__ __align__(16) float gB2[32];        // wave1-private

    const int tid = threadIdx.x;
    const int b   = blockIdx.x;

    if (tid < 64) {
        // ============================ WAVE 0 ============================
        const int l = tid;

        // ---- per-lane weight preload ----
        float wdz1[10]; float bdz1 = 0.f;
        #pragma unroll
        for (int k = 0; k < 10; ++k) wdz1[k] = 0.f;
        if (l < 20) {
            #pragma unroll
            for (int k = 0; k < 10; ++k) wdz1[k] = dz_W1[l * 10 + k];
            bdz1 = dz_b1[l];
        }
        float wzl1[20], wzs1[20];
        #pragma unroll
        for (int k = 0; k < 20; ++k) { wzl1[k] = dz_Wloc[l * 20 + k]; wzs1[k] = dz_Wscale[l * 20 + k]; }
        const float bzl1 = dz_bloc[l], bzs1 = dz_bscale[l];
        float wzl2[20], wzs2[20]; float bzl2 = 0.f, bzs2 = 0.f;
        #pragma unroll
        for (int k = 0; k < 20; ++k) { wzl2[k] = 0.f; wzs2[k] = 0.f; }
        if (l < 36) {
            const int j2 = l + 64;
            #pragma unroll
            for (int k = 0; k < 20; ++k) { wzl2[k] = dz_Wloc[j2 * 20 + k]; wzs2[k] = dz_Wscale[j2 * 20 + k]; }
            bzl2 = dz_bloc[j2]; bzs2 = dz_bscale[j2];
        }
        const int gi_i = l >> 1, gi_h = l & 1;
        float wA[52]; float bihA = 0.f, bhh1r = 0.f; float whh1r[10];
        #pragma unroll
        for (int k = 0; k < 52; ++k) wA[k] = 0.f;
        #pragma unroll
        for (int k = 0; k < 10; ++k) whh1r[k] = 0.f;
        if (l < 60) {
            const int k0 = gi_h ? 52 : 0;
            const int kn = gi_h ? 48 : 52;
            #pragma unroll
            for (int k = 0; k < 52; ++k) if (k < kn) wA[k] = W_ih1[gi_i * 100 + k0 + k];
            bihA = b_ih1[gi_i];
            if (gi_h == 0) {
                #pragma unroll
                for (int k = 0; k < 10; ++k) whh1r[k] = W_hh1[gi_i * 10 + k];
                bhh1r = b_hh1[gi_i];
            }
        }

        // ---- prologue ----
        if (l < 10) h1d[0][l] = h1_0[l];
        if (l < 4)  zbuf[100 + l] = 0.f;
        float e1c = eps[(size_t)b * NT * DHZ + l];
        float e2c = 0.f;
        if (l < 36) e2c = eps[(size_t)b * NT * DHZ + 64 + l];

        for (int w = 0; w < 64; ++w) {
            #pragma unroll 2
            for (int i = 0; i < 8; ++i) {
                const int t  = 8 * w + i;
                const int rs = t & (RING - 1);
                const int wsl = (t + 1) & (RING - 1);
                float h1r[10];
                {
                    float4 a = *(const float4*)&h1d[rs][0];
                    float4 c = *(const float4*)&h1d[rs][4];
                    h1r[0]=a.x; h1r[1]=a.y; h1r[2]=a.z; h1r[3]=a.w;
                    h1r[4]=c.x; h1r[5]=c.y; h1r[6]=c.z; h1r[7]=c.w;
                    h1r[8]=h1d[rs][8]; h1r[9]=h1d[rs][9];
                }
                // prefetch eps(t+1)
                const int tn = (t + 1 < NT) ? (t + 1) : t;
                const float* ern = eps + ((size_t)b * NT + tn) * DHZ;
                float e1n = ern[l];
                float e2n = 0.f;
                if (l < 36) e2n = ern[64 + l];

                // hdz = relu(dz_W1 @ h1 + b)
                if (l < 20) {
                    float v = bdz1;
                    #pragma unroll
                    for (int k = 0; k < 10; ++k) v = fmaf(wdz1[k], h1r[k], v);
                    hdzs[l] = fmaxf(v, 0.f);
                }
                __builtin_amdgcn_wave_barrier();
                float hdzr[20];
                #pragma unroll
                for (int q = 0; q < 5; ++q) {
                    float4 h4 = *(const float4*)&hdzs[4 * q];
                    hdzr[4*q]=h4.x; hdzr[4*q+1]=h4.y; hdzr[4*q+2]=h4.z; hdzr[4*q+3]=h4.w;
                }

                const size_t ob = ((size_t)b * NT + t) * DOUT;
                {
                    float vl = bzl1, vs = bzs1;
                    #pragma unroll
                    for (int k = 0; k < 20; ++k) { vl = fmaf(wzl1[k], hdzr[k], vl); vs = fmaf(wzs1[k], hdzr[k], vs); }
                    float sp = sftp(vs);
                    float zt = fmaf(sp, e1c, vl);
                    zbuf[l] = zt;
                    out[ob + 200 + l] = vl;
                    out[ob + 300 + l] = sp;
                    out[ob + 400 + l] = zt;
                }
                if (l < 36) {
                    float vl = bzl2, vs = bzs2;
                    #pragma unroll
                    for (int k = 0; k < 20; ++k) { vl = fmaf(wzl2[k], hdzr[k], vl); vs = fmaf(wzs2[k], hdzr[k], vs); }
                    float sp = sftp(vs);
                    float zt = fmaf(sp, e2c, vl);
                    zbuf[64 + l] = zt;
                    out[ob + 264 + l] = vl;
                    out[ob + 364 + l] = sp;
                    out[ob + 464 + l] = zt;
                }
                e1c = e1n; e2c = e2n;
                __builtin_amdgcn_wave_barrier();

                // gi1 = W_ih1 @ z_t (split-K lane pairs), gh1 = W_hh1 @ h1
                if (l < 60) {
                    const float4* z4 = (const float4*)zbuf;
                    const int b4 = gi_h ? 13 : 0;
                    float a0=0.f, a1=0.f, a2=0.f, a3=0.f;
                    #pragma unroll
                    for (int q = 0; q < 13; ++q) {
                        float4 zz = z4[b4 + q];
                        a0 = fmaf(wA[4*q+0], zz.x, a0);
                        a1 = fmaf(wA[4*q+1], zz.y, a1);
                        a2 = fmaf(wA[4*q+2], zz.z, a2);
                        a3 = fmaf(wA[4*q+3], zz.w, a3);
                    }
                    float acc = (a0 + a1) + (a2 + a3);
                    acc += __shfl_xor(acc, 1, 64);
                    if (gi_h == 0) {
                        float gh = bhh1r;
                        #pragma unroll
                        for (int k = 0; k < 10; ++k) gh = fmaf(whh1r[k], h1r[k], gh);
                        gA[gi_i] = acc + bihA;
                        gB[gi_i] = gh;
                    }
                }
                __builtin_amdgcn_wave_barrier();

                if (l < 10) {
                    float r = sgm(gA[l] + gB[l]);
                    float u = sgm(gA[l + 10] + gB[l + 10]);
                    float n = tnh(fmaf(r, gB[l + 20], gA[l + 20]));
                    h1d[wsl][l] = (1.f - u) * n + u * h1r[l];
                }
                __builtin_amdgcn_wave_barrier();
            }
            __syncthreads();   // end of window w
        }
        __syncthreads();       // window 64 (wave1 epilogue window)
    } else {
        // ============================ WAVE 1 ============================
        const int l = tid - 64;

        // ---- per-lane weight preload ----
        float wdx1[20]; float bdx1 = 0.f;
        #pragma unroll
        for (int k = 0; k < 20; ++k) wdx1[k] = 0.f;
        if (l < 20) {
            #pragma unroll
            for (int k = 0; k < 20; ++k) wdx1[k] = dx_W1[l * 20 + k];
            bdx1 = dx_b1[l];
        }
        float wxl1[20], wxs1[20];
        #pragma unroll
        for (int k = 0; k < 20; ++k) { wxl1[k] = dx_Wloc[l * 20 + k]; wxs1[k] = dx_Wscale[l * 20 + k]; }
        const float bxl1 = dx_bloc[l], bxs1 = dx_bscale[l];
        float wxl2[20], wxs2[20]; float bxl2 = 0.f, bxs2 = 0.f;
        #pragma unroll
        for (int k = 0; k < 20; ++k) { wxl2[k] = 0.f; wxs2[k] = 0.f; }
        if (l < 36) {
            const int j2 = l + 64;
            #pragma unroll
            for (int k = 0; k < 20; ++k) { wxl2[k] = dx_Wloc[j2 * 20 + k]; wxs2[k] = dx_Wscale[j2 * 20 + k]; }
            bxl2 = dx_bloc[j2]; bxs2 = dx_bscale[j2];
        }
        const int gi_i = l >> 1, gi_h = l & 1;
        float wB[52]; float bihB = 0.f, bhh2r = 0.f; float whh2r[10];
        #pragma unroll
        for (int k = 0; k < 52; ++k) wB[k] = 0.f;
        #pragma unroll
        for (int k = 0; k < 10; ++k) whh2r[k] = 0.f;
        if (l < 60) {
            const int k0 = gi_h ? 52 : 0;
            const int kn = gi_h ? 48 : 52;
            #pragma unroll
            for (int k = 0; k < 52; ++k) if (k < kn) wB[k] = W_ih2[gi_i * 100 + k0 + k];
            bihB = b_ih2[gi_i];
            if (gi_h == 0) {
                #pragma unroll
                for (int k = 0; k < 10; ++k) whh2r[k] = W_hh2[gi_i * 10 + k];
                bhh2r = b_hh2[gi_i];
            }
        }
        float h2r[10];
        #pragma unroll
        for (int k = 0; k < 10; ++k) h2r[k] = h2_0[k];

        // ---- prologue: x row 0 -> xbuf[0], row 1 -> vh ----
        if (l < 4) { xbuf[0][100 + l] = 0.f; xbuf[1][100 + l] = 0.f; }
        float4 vh = make_float4(0.f, 0.f, 0.f, 0.f);
        if (l < 25) {
            const float4* xr0 = (const float4*)(x + (size_t)b * NT * DHX);
            const float4* xr1 = (const float4*)(x + ((size_t)b * NT + 1) * DHX);
            float4 v0 = xr0[l];
            vh = xr1[l];
            *((float4*)&xbuf[0][0] + l) = v0;
        }

        __syncthreads();       // window 0 (wave0 fills h1 slots 1..8)
        for (int w = 1; w < 65; ++w) {
            #pragma unroll 2
            for (int i = 0; i < 8; ++i) {
                const int t = 8 * (w - 1) + i;

                // publish x(t+1); prefetch x(t+2)
                if (l < 25) *((float4*)&xbuf[(t + 1) & 1][0] + l) = vh;
                {
                    const int tn = (t + 2 < NT) ? (t + 2) : (NT - 1);
                    const float4* xr = (const float4*)(x + ((size_t)b * NT + tn) * DHX);
                    if (l < 25) vh = xr[l];
                }

                // dx MLP for step t: h1n(t) = ring slot (t+1), h2_shift(t) = h2r
                const int hs = (t + 1) & (RING - 1);
                if (l < 20) {
                    float4 a = *(const float4*)&h1d[hs][0];
                    float4 c = *(const float4*)&h1d[hs][4];
                    float v = bdx1;
                    v = fmaf(wdx1[0], a.x, v); v = fmaf(wdx1[1], a.y, v);
                    v = fmaf(wdx1[2], a.z, v); v = fmaf(wdx1[3], a.w, v);
                    v = fmaf(wdx1[4], c.x, v); v = fmaf(wdx1[5], c.y, v);
                    v = fmaf(wdx1[6], c.z, v); v = fmaf(wdx1[7], c.w, v);
                    v = fmaf(wdx1[8], h1d[hs][8], v); v = fmaf(wdx1[9], h1d[hs][9], v);
                    #pragma unroll
                    for (int k = 0; k < 10; ++k) v = fmaf(wdx1[10 + k], h2r[k], v);
                    hdxs[l] = fmaxf(v, 0.f);
                }
                __builtin_amdgcn_wave_barrier();
                float hdxr[20];
                #pragma unroll
                for (int q = 0; q < 5; ++q) {
                    float4 h4 = *(const float4*)&hdxs[4 * q];
                    hdxr[4*q]=h4.x; hdxr[4*q+1]=h4.y; hdxr[4*q+2]=h4.z; hdxr[4*q+3]=h4.w;
                }
                const size_t ob = ((size_t)b * NT + t) * DOUT;
                {
                    float vl = bxl1, vs = bxs1;
                    #pragma unroll
                    for (int k = 0; k < 20; ++k) { vl = fmaf(wxl1[k], hdxr[k], vl); vs = fmaf(wxs1[k], hdxr[k], vs); }
                    out[ob + l]       = vl;
                    out[ob + 100 + l] = sftp(vs);
                }
                if (l < 36) {
                    float vl = bxl2, vs = bxs2;
                    #pragma unroll
                    for (int k = 0; k < 20; ++k) { vl = fmaf(wxl2[k], hdxr[k], vl); vs = fmaf(wxs2[k], hdxr[k], vs); }
                    out[ob + 64 + l]  = vl;
                    out[ob + 164 + l] = sftp(vs);
                }
                __builtin_amdgcn_wave_barrier();

                // gi2 = W_ih2 @ x_t (split-K), gh2 = W_hh2 @ h2
                if (l < 60) {
                    const float4* x4 = (const float4*)&xbuf[t & 1][0];
                    const int b4 = gi_h ? 13 : 0;
                    float a0=0.f, a1=0.f, a2=0.f, a3=0.f;
                    #pragma unroll
                    for (int q = 0; q < 13; ++q) {
                        float4 xx = x4[b4 + q];
                        a0 = fmaf(wB[4*q+0], xx.x, a0);
                        a1 = fmaf(wB[4*q+1], xx.y, a1);
                        a2 = fmaf(wB[4*q+2], xx.z, a2);
                        a3 = fmaf(wB[4*q+3], xx.w, a3);
                    }
                    float acc = (a0 + a1) + (a2 + a3);
                    acc += __shfl_xor(acc, 1, 64);
                    if (gi_h == 0) {
                        float gh = bhh2r;
                        #pragma unroll
                        for (int k = 0; k < 10; ++k) gh = fmaf(whh2r[k], h2r[k], gh);
                        gA2[gi_i] = acc + bihB;
                        gB2[gi_i] = gh;
                    }
                }
                __builtin_amdgcn_wave_barrier();
                if (l < 10) {
                    float r = sgm(gA2[l] + gB2[l]);
                    float u = sgm(gA2[l + 10] + gB2[l + 10]);
                    float n = tnh(fmaf(r, gB2[l + 20], gA2[l + 20]));
                    h2new[l] = (1.f - u) * n + u * h2r[l];
                }
                __builtin_amdgcn_wave_barrier();
                {
                    float4 a = *(const float4*)&h2new[0];
                    float4 c = *(const float4*)&h2new[4];
                    h2r[0]=a.x; h2r[1]=a.y; h2r[2]=a.z; h2r[3]=a.w;
                    h2r[4]=c.x; h2r[5]=c.y; h2r[6]=c.z; h2r[7]=c.w;
                    h2r[8]=h2new[8]; h2r[9]=h2new[9];
                }
            }
            __syncthreads();   // end of window w
        }
    }
}

extern "C" void kernel_launch(void* const* d_in, const int* in_sizes, int n_in,
                              void* d_out, int out_size, void* d_ws, size_t ws_size,
                              hipStream_t stream) {
    (void)in_sizes; (void)n_in; (void)out_size; (void)d_ws; (void)ws_size;
    const float* x         = (const float*)d_in[0];
    const float* eps       = (const float*)d_in[1];
    const float* W_ih1     = (const float*)d_in[2];
    const float* W_hh1     = (const float*)d_in[3];
    const float* b_ih1     = (const float*)d_in[4];
    const float* b_hh1     = (const float*)d_in[5];
    const float* W_ih2     = (const float*)d_in[6];
    const float* W_hh2     = (const float*)d_in[7];
    const float* b_ih2     = (const float*)d_in[8];
    const float* b_hh2     = (const float*)d_in[9];
    const float* dz_W1     = (const float*)d_in[10];
    const float* dz_b1     = (const float*)d_in[11];
    const float* dz_Wloc   = (const float*)d_in[12];
    const float* dz_bloc   = (const float*)d_in[13];
    const float* dz_Wscale = (const float*)d_in[14];
    const float* dz_bscale = (const float*)d_in[15];
    const float* dx_W1     = (const float*)d_in[16];
    const float* dx_b1     = (const float*)d_in[17];
    const float* dx_Wloc   = (const float*)d_in[18];
    const float* dx_bloc   = (const float*)d_in[19];
    const float* dx_Wscale = (const float*)d_in[20];
    const float* dx_bscale = (const float*)d_in[21];
    const float* h1_0      = (const float*)d_in[22];
    const float* h2_0      = (const float*)d_in[23];

    arfssm<<<NB, 128, 0, stream>>>(x, eps, W_ih1, W_hh1, b_ih1, b_hh1,
                                   W_ih2, W_hh2, b_ih2, b_hh2,
                                   dz_W1, dz_b1, dz_Wloc, dz_bloc, dz_Wscale, dz_bscale,
                                   dx_W1, dx_b1, dx_Wloc, dx_bloc, dx_Wscale, dx_bscale,
                                   h1_0, h2_0, (float*)d_out);
}